// Round 9
// baseline (473.070 us; speedup 1.0000x reference)
//
#include <hip/hip_runtime.h>

#define TT 512
#define BIGS 1.4426950408889634e10f   // BIG(1e10) * log2(e), scaled domain
#define LOG2E 1.4426950408889634f
#define M2L  (-2.0f * 1.4426950408889634f)
#define LN2F 0.69314718055994531f

typedef float f2v __attribute__((ext_vector_type(2)));

// ---------------------------------------------------------------------------
// Column-marching lane-skewed SoftDTW, fp32 distance path. One wave per
// sample. Lane t owns rows 8t..8t+7 (X as 128 fp32 VGPRs); at tick tau it
// processes the 8-cell vertical strip of column j = tau - t (one shared Z
// row per tick). Cross-lane: one __shfl_up per tick. 576 ticks, no barriers.
// Distances via v_pk_fma_f32-able float2 FMAs (full-rate), replacing the
// f16 dot path measured at ~20 cyc/op across rounds 3/5/7/8. Z rows are
// prefetched 2 ticks ahead (ping-pong regs) from a 32 KiB fp32 LDS image;
// dd for tick tv+1 is computed in tick tv (independent of the softmin
// chain), so the chain overlaps the FMA issue. Borders exact by BIGS
// initialization (exp2(x-BIGS)==0), no masking except the per-lane j-range
// guard. Base-2 scaled domain (values = true * log2(e)).
// ---------------------------------------------------------------------------
__global__ __launch_bounds__(64, 1) void k_fused(const float* __restrict__ X,
                                                 const float* __restrict__ Z,
                                                 const float* __restrict__ w,
                                                 float* __restrict__ out) {
    const int n = blockIdx.x;
    const int t = threadIdx.x;

    __shared__ float4 Zf[512][4];   // Z rows fp32, 64 B/row, 32 KiB
    __shared__ float  zs2[512];     // LOG2E * |z_row|^2

    // ---- stage Z into LDS ----
#pragma unroll
    for (int rr = 0; rr < 8; ++rr) {
        const int r = rr * 64 + t;
        const float4* zp = (const float4*)(Z + (size_t)r * 16);
        const float4 a0 = zp[0], a1 = zp[1], a2 = zp[2], a3 = zp[3];
        float sv = 0.0f;
        sv = fmaf(a0.x, a0.x, sv); sv = fmaf(a0.y, a0.y, sv);
        sv = fmaf(a0.z, a0.z, sv); sv = fmaf(a0.w, a0.w, sv);
        sv = fmaf(a1.x, a1.x, sv); sv = fmaf(a1.y, a1.y, sv);
        sv = fmaf(a1.z, a1.z, sv); sv = fmaf(a1.w, a1.w, sv);
        sv = fmaf(a2.x, a2.x, sv); sv = fmaf(a2.y, a2.y, sv);
        sv = fmaf(a2.z, a2.z, sv); sv = fmaf(a2.w, a2.w, sv);
        sv = fmaf(a3.x, a3.x, sv); sv = fmaf(a3.y, a3.y, sv);
        sv = fmaf(a3.z, a3.z, sv); sv = fmaf(a3.w, a3.w, sv);
        Zf[r][0] = a0; Zf[r][1] = a1; Zf[r][2] = a2; Zf[r][3] = a3;
        zs2[r] = LOG2E * sv;
    }

    // ---- X rows for this lane -> fp32 registers (128 VGPRs) ----
    f2v   Xf[8][8];
    float xs2[8];
    const float* xp = X + ((size_t)n * TT + 8 * t) * 16;
#pragma unroll
    for (int q = 0; q < 8; ++q) {
        const float4* xr = (const float4*)(xp + q * 16);
        const float4 a0 = xr[0], a1 = xr[1], a2 = xr[2], a3 = xr[3];
        float sv = 0.0f;
        sv = fmaf(a0.x, a0.x, sv); sv = fmaf(a0.y, a0.y, sv);
        sv = fmaf(a0.z, a0.z, sv); sv = fmaf(a0.w, a0.w, sv);
        sv = fmaf(a1.x, a1.x, sv); sv = fmaf(a1.y, a1.y, sv);
        sv = fmaf(a1.z, a1.z, sv); sv = fmaf(a1.w, a1.w, sv);
        sv = fmaf(a2.x, a2.x, sv); sv = fmaf(a2.y, a2.y, sv);
        sv = fmaf(a2.z, a2.z, sv); sv = fmaf(a2.w, a2.w, sv);
        sv = fmaf(a3.x, a3.x, sv); sv = fmaf(a3.y, a3.y, sv);
        sv = fmaf(a3.z, a3.z, sv); sv = fmaf(a3.w, a3.w, sv);
        xs2[q] = LOG2E * sv;
        Xf[q][0] = (f2v){a0.x, a0.y}; Xf[q][1] = (f2v){a0.z, a0.w};
        Xf[q][2] = (f2v){a1.x, a1.y}; Xf[q][3] = (f2v){a1.z, a1.w};
        Xf[q][4] = (f2v){a2.x, a2.y}; Xf[q][5] = (f2v){a2.z, a2.w};
        Xf[q][6] = (f2v){a3.x, a3.y}; Xf[q][7] = (f2v){a3.z, a3.w};
    }
    const float wgt = w[n];
    __syncthreads();

    float Rp[8];
#pragma unroll
    for (int q = 0; q < 8; ++q) Rp[q] = BIGS;
    float u_old = (t == 0) ? 0.0f : BIGS;   // diag input; lane0 tick0 = corner

    f2v   Zr[2][8];     // ping-pong Z-row buffers (fp32 pairs)
    float zsb[2];
    float ddA[8], ddB[8];

    // ---- prime: dd for tick 0 (row 0 broadcast; only lane0 valid) ----
    {
        const float4 v0 = Zf[0][0], v1 = Zf[0][1], v2 = Zf[0][2], v3 = Zf[0][3];
        f2v z[8] = {(f2v){v0.x, v0.y}, (f2v){v0.z, v0.w},
                    (f2v){v1.x, v1.y}, (f2v){v1.z, v1.w},
                    (f2v){v2.x, v2.y}, (f2v){v2.z, v2.w},
                    (f2v){v3.x, v3.y}, (f2v){v3.z, v3.w}};
        const float zz = zs2[0];
#pragma unroll
        for (int q = 0; q < 8; ++q) {
            f2v acc = z[0] * Xf[q][0];
#pragma unroll
            for (int r = 1; r < 8; ++r)
                acc = __builtin_elementwise_fma(z[r], Xf[q][r], acc);
            ddA[q] = fmaf(M2L, acc.x + acc.y, xs2[q] + zz);
        }
    }
    // ---- prime: slot 1 <- Z row for tick 1 (j = 1 - t, clamped) ----
    {
        int jn = 1 - t; jn = jn < 0 ? 0 : jn;
        const float4 v0 = Zf[jn][0], v1 = Zf[jn][1], v2 = Zf[jn][2], v3 = Zf[jn][3];
        Zr[1][0] = (f2v){v0.x, v0.y}; Zr[1][1] = (f2v){v0.z, v0.w};
        Zr[1][2] = (f2v){v1.x, v1.y}; Zr[1][3] = (f2v){v1.z, v1.w};
        Zr[1][4] = (f2v){v2.x, v2.y}; Zr[1][5] = (f2v){v2.z, v2.w};
        Zr[1][6] = (f2v){v3.x, v3.y}; Zr[1][7] = (f2v){v3.z, v3.w};
        zsb[1] = zs2[jn];
#pragma unroll
        for (int r = 0; r < 8; ++r) Zr[0][r] = Zr[1][r];
        zsb[0] = zsb[1];
    }

    // tick tv (par = tv&1): shfl; prefetch row tv+2 into slot par; compute
    // dd for tick tv+1 from slot 1-par (loaded last tick); softmin chain
    // for tick tv using DDC (computed last tick).
#define TICK(par, tv, DDC, DDN)                                                \
    {                                                                          \
        float u_new = __shfl_up(Rp[7], 1);                                     \
        if (t == 0) u_new = BIGS;                                              \
        {                                                                      \
            int jn = (tv) + 2 - t;                                             \
            jn = jn < 0 ? 0 : (jn > 511 ? 511 : jn);                           \
            const float4 v0 = Zf[jn][0], v1 = Zf[jn][1];                       \
            const float4 v2 = Zf[jn][2], v3 = Zf[jn][3];                       \
            Zr[par][0] = (f2v){v0.x, v0.y}; Zr[par][1] = (f2v){v0.z, v0.w};    \
            Zr[par][2] = (f2v){v1.x, v1.y}; Zr[par][3] = (f2v){v1.z, v1.w};    \
            Zr[par][4] = (f2v){v2.x, v2.y}; Zr[par][5] = (f2v){v2.z, v2.w};    \
            Zr[par][6] = (f2v){v3.x, v3.y}; Zr[par][7] = (f2v){v3.z, v3.w};    \
            zsb[par] = zs2[jn];                                                \
        }                                                                      \
        _Pragma("unroll")                                                      \
        for (int q = 0; q < 8; ++q) {                                          \
            f2v acc = Zr[1 - (par)][0] * Xf[q][0];                             \
            acc = __builtin_elementwise_fma(Zr[1 - (par)][1], Xf[q][1], acc);  \
            acc = __builtin_elementwise_fma(Zr[1 - (par)][2], Xf[q][2], acc);  \
            acc = __builtin_elementwise_fma(Zr[1 - (par)][3], Xf[q][3], acc);  \
            acc = __builtin_elementwise_fma(Zr[1 - (par)][4], Xf[q][4], acc);  \
            acc = __builtin_elementwise_fma(Zr[1 - (par)][5], Xf[q][5], acc);  \
            acc = __builtin_elementwise_fma(Zr[1 - (par)][6], Xf[q][6], acc);  \
            acc = __builtin_elementwise_fma(Zr[1 - (par)][7], Xf[q][7], acc);  \
            DDN[q] = fmaf(M2L, acc.x + acc.y, xs2[q] + zsb[1 - (par)]);        \
        }                                                                      \
        const int j = (tv) - t;                                                \
        if (j >= 0 && j < 512) {                                               \
            float up = u_new, pd = u_old;                                      \
            _Pragma("unroll")                                                  \
            for (int q = 0; q < 8; ++q) {                                      \
                const float pl = Rp[q];                                        \
                const float mn = fminf(fminf(up, pl), pd);                     \
                const float md = __builtin_amdgcn_fmed3f(up, pl, pd);          \
                const float mx = fmaxf(fmaxf(up, pl), pd);                     \
                const float sm = 1.0f + exp2f(mn - md) + exp2f(mn - mx);       \
                const float v = DDC[q] + mn - log2f(sm);                       \
                pd = pl;                                                       \
                Rp[q] = v;                                                     \
                up = v;                                                        \
            }                                                                  \
        }                                                                      \
        u_old = u_new;                                                         \
    }

#pragma unroll 1
    for (int tau = 0; tau < 576; tau += 2) {
        TICK(0, tau, ddA, ddB)
        TICK(1, tau + 1, ddB, ddA)
    }
#undef TICK

    // lane 63 Rp[7] = R[511][511] (scaled); unscale and accumulate
    if (t == 63) atomicAdd(out, wgt * Rp[7] * LN2F);
}

__global__ void k_zero(float* out) {
    if (threadIdx.x == 0) out[0] = 0.0f;
}

extern "C" void kernel_launch(void* const* d_in, const int* in_sizes, int n_in,
                              void* d_out, int out_size, void* d_ws, size_t ws_size,
                              hipStream_t stream) {
    const float* X = (const float*)d_in[0];   // (64, 512, 16) f32
    const float* w = (const float*)d_in[1];   // (64,) f32
    const float* Z = (const float*)d_in[2];   // (512, 16) f32
    float* out = (float*)d_out;               // scalar f32

    hipLaunchKernelGGL(k_zero, dim3(1), dim3(64), 0, stream, out);
    hipLaunchKernelGGL(k_fused, dim3(64), dim3(64), 0, stream, X, Z, w, out);
}

// Round 10
// 268.628 us; speedup vs baseline: 1.7611x; 1.7611x over previous
//
#include <hip/hip_runtime.h>

#define TT 512
#define BIGS 1.4426950408889634e10f   // BIG(1e10) * log2(e), scaled domain
#define LOG2E 1.4426950408889634f
#define M2L  (-2.0f * 1.4426950408889634f)
#define LN2F 0.69314718055994531f
#define P_SS 16                       // ticks per superstep (barrier period)
#define G_LAG 80                      // band lag in ticks (>= P_SS + 63)
#define N_SS 51                       // wave3 last tick 574+240=814 -> s=50

typedef _Float16 h2 __attribute__((ext_vector_type(2)));

__device__ __forceinline__ unsigned pk(float a, float b) {
    h2 v; v.x = (_Float16)a; v.y = (_Float16)b;
    return __builtin_bit_cast(unsigned, v);
}

#if __has_builtin(__builtin_amdgcn_fdot2)
#define FDOT2(a, b, c) __builtin_amdgcn_fdot2(__builtin_bit_cast(h2, (a)), \
                                              __builtin_bit_cast(h2, (b)), (c), false)
#else
__device__ __forceinline__ float fdot2_sw(unsigned a, unsigned b, float c) {
    h2 ha = __builtin_bit_cast(h2, a), hb = __builtin_bit_cast(h2, b);
    return c + (float)ha.x * (float)hb.x + (float)ha.y * (float)hb.y;
}
#define FDOT2(a, b, c) fdot2_sw((a), (b), (c))
#endif

// ---------------------------------------------------------------------------
// Banded column-marching SoftDTW in (K, sm) log-sum-exp split form.
// One block (256 thr = 4 waves) per sample; wave w owns rows [128w,128w+128),
// lane t owns rows 128w+2t, 128w+2t+1. Column-march: at local tick tau lane t
// does column j = tau - t (2 cells). R = K - log2(sm) carried as a pair:
//   m^ = min3(K_up,K_left,K_diag); sm' = sum exp2(m^-K_i)*sm_i; K' = dd + m^.
// -> NO log2 in the recurrence (one at the very end); K-chain = min3+add.
// Power-of-2 renorm (exact) every 8 ticks keeps sm in range. Borders exact
// via (BIGS, 1) pairs: exp2(m^-BIGS)==0. Bands pipelined with lag G_LAG=80,
// barrier every P_SS=16 ticks (write->read always crosses a barrier; 64-slot
// column ring, max writer/reader span 63). Z rows fp16 in the permuted
// low-conflict LDS layout; one new Z row per tick, ping-pong prefetched.
// ---------------------------------------------------------------------------
__global__ __launch_bounds__(256, 1) void k_fused(const float* __restrict__ X,
                                                  const float* __restrict__ Z,
                                                  const float* __restrict__ w,
                                                  float* __restrict__ out) {
    const int tt = threadIdx.x;
    const int t  = tt & 63;          // lane
    const int wv = tt >> 6;          // wave = row band 0..3
    const int n  = blockIdx.x;       // sample

    __shared__ uint4 ZA[2][512];     // Z rows fp16-packed, permuted idx
    __shared__ float Zs2p[512];      // LOG2E*|z|^2 at permuted idx
    __shared__ float seamK[4][64];   // seam rings (K); level 0 = const border
    __shared__ float seamS[4][64];   // seam rings (sm)

    // ---- stage Z into LDS: thread tt handles rows tt, tt+256 ----
#pragma unroll
    for (int h = 0; h < 2; ++h) {
        const int r = tt + h * 256;
        const float4* zp = (const float4*)(Z + (size_t)r * 16);
        const float4 a0 = zp[0], a1 = zp[1], a2 = zp[2], a3 = zp[3];
        float sv = 0.0f;
        sv = fmaf(a0.x, a0.x, sv); sv = fmaf(a0.y, a0.y, sv);
        sv = fmaf(a0.z, a0.z, sv); sv = fmaf(a0.w, a0.w, sv);
        sv = fmaf(a1.x, a1.x, sv); sv = fmaf(a1.y, a1.y, sv);
        sv = fmaf(a1.z, a1.z, sv); sv = fmaf(a1.w, a1.w, sv);
        sv = fmaf(a2.x, a2.x, sv); sv = fmaf(a2.y, a2.y, sv);
        sv = fmaf(a2.z, a2.z, sv); sv = fmaf(a2.w, a2.w, sv);
        sv = fmaf(a3.x, a3.x, sv); sv = fmaf(a3.y, a3.y, sv);
        sv = fmaf(a3.z, a3.z, sv); sv = fmaf(a3.w, a3.w, sv);
        const int idx = ((r & 1) << 8) | (r >> 1);
        ZA[0][idx] = make_uint4(pk(a0.x, a0.y), pk(a0.z, a0.w),
                                pk(a1.x, a1.y), pk(a1.z, a1.w));
        ZA[1][idx] = make_uint4(pk(a2.x, a2.y), pk(a2.z, a2.w),
                                pk(a3.x, a3.y), pk(a3.z, a3.w));
        Zs2p[idx] = LOG2E * sv;
    }
    // seam rings -> (BIGS, 1): matrix border; level 0 is never written
    (&seamK[0][0])[tt] = BIGS;
    (&seamS[0][0])[tt] = 1.0f;

    // ---- X rows for this lane (rows i0, i0+1) -> registers ----
    const int i0 = 128 * wv + 2 * t;
    unsigned Xu[2][8];
    float    xs2[2];
    const float* xp = X + ((size_t)n * TT + i0) * 16;
#pragma unroll
    for (int q = 0; q < 2; ++q) {
        const float4* xr = (const float4*)(xp + q * 16);
        const float4 a0 = xr[0], a1 = xr[1], a2 = xr[2], a3 = xr[3];
        float sv = 0.0f;
        sv = fmaf(a0.x, a0.x, sv); sv = fmaf(a0.y, a0.y, sv);
        sv = fmaf(a0.z, a0.z, sv); sv = fmaf(a0.w, a0.w, sv);
        sv = fmaf(a1.x, a1.x, sv); sv = fmaf(a1.y, a1.y, sv);
        sv = fmaf(a1.z, a1.z, sv); sv = fmaf(a1.w, a1.w, sv);
        sv = fmaf(a2.x, a2.x, sv); sv = fmaf(a2.y, a2.y, sv);
        sv = fmaf(a2.z, a2.z, sv); sv = fmaf(a2.w, a2.w, sv);
        sv = fmaf(a3.x, a3.x, sv); sv = fmaf(a3.y, a3.y, sv);
        sv = fmaf(a3.z, a3.z, sv); sv = fmaf(a3.w, a3.w, sv);
        xs2[q] = LOG2E * sv;
        Xu[q][0] = pk(a0.x, a0.y); Xu[q][1] = pk(a0.z, a0.w);
        Xu[q][2] = pk(a1.x, a1.y); Xu[q][3] = pk(a1.z, a1.w);
        Xu[q][4] = pk(a2.x, a2.y); Xu[q][5] = pk(a2.z, a2.w);
        Xu[q][6] = pk(a3.x, a3.y); Xu[q][7] = pk(a3.z, a3.w);
    }
    const float wgt = w[n];
    __syncthreads();

    float RpK[2], RpS[2];            // R pairs for my 2 rows, prev column
    float poK, poS;                  // diag input (prev tick's up)
    float smK, smS;                  // prefetched seam value (lane-0 up)
    uint4 Zb[2][2];                  // ping-pong Z row (fp16, 2 halves)
    float zsb[2];
    RpK[0] = RpK[1] = BIGS; RpS[0] = RpS[1] = 1.0f;
    poK = BIGS; poS = 1.0f; smK = BIGS; smS = 1.0f;
    zsb[0] = zsb[1] = 0.0f;
    Zb[0][0] = Zb[0][1] = Zb[1][0] = Zb[1][1] = make_uint4(0, 0, 0, 0);

    // One tick: cells (i0, j) and (i0+1, j), j = tau - t.
#define TICK(par, tau)                                                         \
    {                                                                          \
        float unK = __shfl_up(RpK[1], 1);                                      \
        float unS = __shfl_up(RpS[1], 1);                                      \
        if (t == 0) { unK = smK; unS = smS; }                                  \
        smK = seamK[wv][((tau) + 1) & 63];   /* prefetch for tick tau+1 */     \
        smS = seamS[wv][((tau) + 1) & 63];                                     \
        {   /* prefetch Z row for tick tau+1 into slot 1-par */                \
            int jn = (tau) + 1 - t;                                            \
            jn = jn < 0 ? 0 : (jn > 511 ? 511 : jn);                           \
            const int xn = ((jn & 1) << 8) | (jn >> 1);                        \
            Zb[1 - (par)][0] = ZA[0][xn];                                      \
            Zb[1 - (par)][1] = ZA[1][xn];                                      \
            zsb[1 - (par)] = Zs2p[xn];                                         \
        }                                                                      \
        const int j = (tau) - t;                                               \
        if (j >= 0 && j < 512) {                                               \
            const uint4 z0 = Zb[(par)][0], z1 = Zb[(par)][1];                  \
            float a0 = 0.0f, a1 = 0.0f;                                        \
            a0 = FDOT2(z0.x, Xu[0][0], a0); a0 = FDOT2(z0.y, Xu[0][1], a0);    \
            a0 = FDOT2(z0.z, Xu[0][2], a0); a0 = FDOT2(z0.w, Xu[0][3], a0);    \
            a0 = FDOT2(z1.x, Xu[0][4], a0); a0 = FDOT2(z1.y, Xu[0][5], a0);    \
            a0 = FDOT2(z1.z, Xu[0][6], a0); a0 = FDOT2(z1.w, Xu[0][7], a0);    \
            a1 = FDOT2(z0.x, Xu[1][0], a1); a1 = FDOT2(z0.y, Xu[1][1], a1);    \
            a1 = FDOT2(z0.z, Xu[1][2], a1); a1 = FDOT2(z0.w, Xu[1][3], a1);    \
            a1 = FDOT2(z1.x, Xu[1][4], a1); a1 = FDOT2(z1.y, Xu[1][5], a1);    \
            a1 = FDOT2(z1.z, Xu[1][6], a1); a1 = FDOT2(z1.w, Xu[1][7], a1);    \
            const float dd0 = fmaf(M2L, a0, xs2[0] + zsb[(par)]);              \
            const float dd1 = fmaf(M2L, a1, xs2[1] + zsb[(par)]);              \
            /* cell 0: up=(unK,unS) left=(RpK0,RpS0) diag=(poK,poS) */         \
            const float l0K = RpK[0], l0S = RpS[0];                            \
            const float m0 = fminf(fminf(unK, l0K), poK);                      \
            const float s0 = exp2f(m0 - unK) * unS                             \
                           + exp2f(m0 - l0K) * l0S                             \
                           + exp2f(m0 - poK) * poS;                            \
            const float K0 = dd0 + m0;                                         \
            /* cell 1: up=(K0,s0) left=(RpK1,RpS1) diag=(l0K,l0S) */           \
            const float l1K = RpK[1], l1S = RpS[1];                            \
            const float m1 = fminf(fminf(K0, l1K), l0K);                       \
            const float s1 = exp2f(m1 - K0) * s0                               \
                           + exp2f(m1 - l1K) * l1S                             \
                           + exp2f(m1 - l0K) * l0S;                            \
            const float K1 = dd1 + m1;                                         \
            RpK[0] = K0; RpS[0] = s0;                                          \
            RpK[1] = K1; RpS[1] = s1;                                          \
            if (wv < 3 && t == 63) {                                           \
                seamK[wv + 1][j & 63] = K1;                                    \
                seamS[wv + 1][j & 63] = s1;                                    \
            }                                                                  \
        }                                                                      \
        poK = unK; poS = unS;                                                  \
    }

    // exact power-of-2 renorm: sm -> [1,2), K -= exponent (no-op at sm==1)
#define RENORM                                                                 \
    {                                                                          \
        _Pragma("unroll")                                                      \
        for (int q = 0; q < 2; ++q) {                                          \
            const int e = (int)(__float_as_uint(RpS[q]) >> 23) - 127;          \
            RpS[q] = __uint_as_float(__float_as_uint(RpS[q])                   \
                                     - ((unsigned)e << 23));                   \
            RpK[q] -= (float)e;                                                \
        }                                                                      \
    }

#pragma unroll 1
    for (int s = 0; s < N_SS; ++s) {
        const int tb = P_SS * s - G_LAG * wv;
        if (tb >= 0 && tb <= 574) {
            if (tb == 0) {
                // activation: state init + prime tick-0 reads
                RpK[0] = RpK[1] = BIGS; RpS[0] = RpS[1] = 1.0f;
                poK = (wv == 0 && t == 0) ? 0.0f : BIGS; poS = 1.0f;  // corner
                smK = seamK[wv][0]; smS = seamS[wv][0];
                Zb[0][0] = ZA[0][0]; Zb[0][1] = ZA[1][0]; zsb[0] = Zs2p[0];
            }
            TICK(0, tb + 0)  TICK(1, tb + 1)  TICK(0, tb + 2)  TICK(1, tb + 3)
            TICK(0, tb + 4)  TICK(1, tb + 5)  TICK(0, tb + 6)  TICK(1, tb + 7)
            RENORM
            TICK(0, tb + 8)  TICK(1, tb + 9)  TICK(0, tb + 10) TICK(1, tb + 11)
            TICK(0, tb + 12) TICK(1, tb + 13) TICK(0, tb + 14) TICK(1, tb + 15)
            RENORM
        }
        __syncthreads();
    }
#undef TICK
#undef RENORM

    // wave 3, lane 63, row 511: R = K - log2(sm); unscale by ln2
    if (wv == 3 && t == 63) {
        atomicAdd(out, wgt * (RpK[1] - log2f(RpS[1])) * LN2F);
    }
}

__global__ void k_zero(float* out) {
    if (threadIdx.x == 0) out[0] = 0.0f;
}

extern "C" void kernel_launch(void* const* d_in, const int* in_sizes, int n_in,
                              void* d_out, int out_size, void* d_ws, size_t ws_size,
                              hipStream_t stream) {
    const float* X = (const float*)d_in[0];   // (64, 512, 16) f32
    const float* w = (const float*)d_in[1];   // (64,) f32
    const float* Z = (const float*)d_in[2];   // (512, 16) f32
    float* out = (float*)d_out;               // scalar f32

    hipLaunchKernelGGL(k_zero, dim3(1), dim3(64), 0, stream, out);
    hipLaunchKernelGGL(k_fused, dim3(64), dim3(256), 0, stream, X, Z, w, out);
}